// Round 1
// baseline (130.315 us; speedup 1.0000x reference)
//
#include <hip/hip_runtime.h>
#include <math.h>

#define EPSQ 1e-8f

__device__ __forceinline__ float rcp_fast(float x) { return __builtin_amdgcn_rcpf(x); }
__device__ __forceinline__ float rsq_fast(float x) { return __builtin_amdgcn_rsqf(x); }

// One thread per (sample n, output capsule o). Block = 256 threads = 16 samples x 16 o.
// Lane layout: tid = ln*16 + o  (o in low 4 bits) so softmax-over-o is a 16-lane
// butterfly that never crosses a wave boundary.
__global__ __launch_bounds__(256, 4) void caps_kernel(
    const float* __restrict__ x,      // [N,16,4]
    const float* __restrict__ quats,  // [16,16,4]
    const float* __restrict__ scale,  // [16,16,1]
    const float* __restrict__ trans,  // [16,16,3]
    const float* __restrict__ bias,   // [16]
    const float* __restrict__ beta,   // [16]
    const float* __restrict__ alpha,  // [16]
    float* __restrict__ out)          // [N,16,4]
{
    // [i][o][4] layout: 16 o-lanes read 16 consecutive float4s -> conflict-free,
    // and the 4 sample-groups of a wave read identical addresses (broadcast).
    __shared__ __align__(16) float qs[16][16][4];  // folded scale * qn  (w,x,y,z)
    __shared__ __align__(16) float tr[16][16][4];  // (0, tx, ty, tz)
    __shared__ __align__(16) float xs[16][68];     // x tile, +4 float row pad

    const int tid = threadIdx.x;
    const int o   = tid & 15;
    const int ln  = tid >> 4;

    // ---- stage params: one thread per (o2,i2) entry; fold scale into qn ----
    {
        const int o2 = tid >> 4, i2 = tid & 15;
        const float4 q = ((const float4*)quats)[tid];     // quats[o2][i2][0:4]
        const float sc = scale[tid];
        const float qn2 = q.x*q.x + q.y*q.y + q.z*q.z + q.w*q.w;
        const float f = sc * rsq_fast(qn2 + EPSQ);
        qs[i2][o2][0] = q.x * f;
        qs[i2][o2][1] = q.y * f;
        qs[i2][o2][2] = q.z * f;
        qs[i2][o2][3] = q.w * f;
        tr[i2][o2][0] = 0.0f;                 // real part untranslated
        tr[i2][o2][1] = trans[tid*3 + 0];
        tr[i2][o2][2] = trans[tid*3 + 1];
        tr[i2][o2][3] = trans[tid*3 + 2];
    }
    // ---- stage x tile: 1024 contiguous floats, one float4 per thread ----
    {
        const float4 xv = ((const float4*)x)[(size_t)blockIdx.x * 256 + tid];
        *(float4*)&xs[tid >> 4][(tid & 15) * 4] = xv;
    }
    __syncthreads();

    // ---- votes[i] = (scale*qn) (x) x[n,i]  + trans   (register-resident) ----
    float4 votes[16];
    #pragma unroll
    for (int i = 0; i < 16; ++i) {
        const float4 q  = *(const float4*)&qs[i][o][0];
        const float4 t  = *(const float4*)&tr[i][o][0];
        const float4 xv = *(const float4*)&xs[ln][i * 4];
        float4 vt;
        // hamilton(q, x): q=(w,x,y,z) in (q.x,q.y,q.z,q.w); same for xv
        vt.x = q.x*xv.x - q.y*xv.y - q.z*xv.z - q.w*xv.w + t.x;
        vt.y = q.x*xv.y + q.y*xv.x + q.z*xv.w - q.w*xv.z + t.y;
        vt.z = q.x*xv.z - q.y*xv.w + q.z*xv.x + q.w*xv.y + t.z;
        vt.w = q.x*xv.w + q.y*xv.z - q.z*xv.y + q.w*xv.x + t.w;
        votes[i] = vt;
    }

    float b[16];
    float4 s, v;

    // ---- routing iter 0: b==0 -> softmax is exactly uniform c = 1/16 ----
    s.x = s.y = s.z = s.w = 0.f;
    #pragma unroll
    for (int i = 0; i < 16; ++i) {
        s.x += votes[i].x; s.y += votes[i].y; s.z += votes[i].z; s.w += votes[i].w;
    }
    s.x *= 0.0625f; s.y *= 0.0625f; s.z *= 0.0625f; s.w *= 0.0625f;
    {
        const float n2 = s.x*s.x + s.y*s.y + s.z*s.z + s.w*s.w;
        const float f = n2 * rcp_fast(1.f + n2) * rsq_fast(n2 + EPSQ);
        v.x = s.x*f; v.y = s.y*f; v.z = s.z*f; v.w = s.w*f;
    }
    #pragma unroll
    for (int i = 0; i < 16; ++i)
        b[i] = v.x*votes[i].x + v.y*votes[i].y + v.z*votes[i].z + v.w*votes[i].w;

    // ---- routing iters 1..2: real softmax over o (cross-lane, width 16) ----
    #pragma unroll
    for (int it = 1; it < 3; ++it) {
        float4 sn; sn.x = sn.y = sn.z = sn.w = 0.f;
        #pragma unroll
        for (int i = 0; i < 16; ++i) {
            const float bi = b[i];
            float m = bi;
            m = fmaxf(m, __shfl_xor(m, 1, 16));
            m = fmaxf(m, __shfl_xor(m, 2, 16));
            m = fmaxf(m, __shfl_xor(m, 4, 16));
            m = fmaxf(m, __shfl_xor(m, 8, 16));
            const float e = __expf(bi - m);
            float se = e;
            se += __shfl_xor(se, 1, 16);
            se += __shfl_xor(se, 2, 16);
            se += __shfl_xor(se, 4, 16);
            se += __shfl_xor(se, 8, 16);
            const float c = e * rcp_fast(se);
            sn.x = fmaf(c, votes[i].x, sn.x);
            sn.y = fmaf(c, votes[i].y, sn.y);
            sn.z = fmaf(c, votes[i].z, sn.z);
            sn.w = fmaf(c, votes[i].w, sn.w);
        }
        s = sn;
        const float n2 = s.x*s.x + s.y*s.y + s.z*s.z + s.w*s.w;
        const float f = n2 * rcp_fast(1.f + n2) * rsq_fast(n2 + EPSQ);
        v.x = s.x*f; v.y = s.y*f; v.z = s.z*f; v.w = s.w*f;
        if (it == 1) {   // last iteration's b-update is dead in the reference
            #pragma unroll
            for (int i = 0; i < 16; ++i)
                b[i] += v.x*votes[i].x + v.y*votes[i].y + v.z*votes[i].z + v.w*votes[i].w;
        }
    }

    // ---- activation + store (coalesced float4 per thread) ----
    const float n2f = s.x*s.x + s.y*s.y + s.z*s.z + s.w*s.w;
    const float norm_s = sqrtf(n2f + EPSQ);
    const float tgt = beta[o] * norm_s + alpha[o] + bias[o];
    const float a = rcp_fast(1.f + __expf(-tgt));
    float4 ov;
    ov.x = v.x * a; ov.y = v.y * a; ov.z = v.z * a; ov.w = v.w * a;
    ((float4*)out)[(size_t)blockIdx.x * 256 + tid] = ov;
}

extern "C" void kernel_launch(void* const* d_in, const int* in_sizes, int n_in,
                              void* d_out, int out_size, void* d_ws, size_t ws_size,
                              hipStream_t stream) {
    const float* x     = (const float*)d_in[0];
    const float* quats = (const float*)d_in[1];
    const float* scale = (const float*)d_in[2];
    const float* trans = (const float*)d_in[3];
    const float* bias  = (const float*)d_in[4];
    const float* beta  = (const float*)d_in[5];
    const float* alpha = (const float*)d_in[6];
    float* out = (float*)d_out;

    const int N = in_sizes[0] / 64;      // x is [N,16,4] -> 65536
    dim3 grid(N / 16), block(256);       // 16 samples per block
    caps_kernel<<<grid, block, 0, stream>>>(x, quats, scale, trans, bias, beta, alpha, out);
}

// Round 2
// 115.950 us; speedup vs baseline: 1.1239x; 1.1239x over previous
//
#include <hip/hip_runtime.h>
#include <math.h>

#define EPSQ 1e-8f

__device__ __forceinline__ float rcp_fast(float x) { return __builtin_amdgcn_rcpf(x); }
__device__ __forceinline__ float rsq_fast(float x) { return __builtin_amdgcn_rsqf(x); }

// DPP cross-lane move: ctrl must be a compile-time constant.
#define DPP_F(x, ctrl) \
    __int_as_float(__builtin_amdgcn_update_dpp(0, __float_as_int(x), (ctrl), 0xF, 0xF, true))

// All-reduce sum over each aligned 16-lane group (pure VALU, no LDS):
// quad butterfly (xor1, xor2) -> quad-uniform, then row_ror:4 + row_ror:8
// combine the four quads of the 16-lane DPP row.
__device__ __forceinline__ float allsum16(float v) {
    v += DPP_F(v, 0xB1);   // quad_perm [1,0,3,2]  == xor 1
    v += DPP_F(v, 0x4E);   // quad_perm [2,3,0,1]  == xor 2
    v += DPP_F(v, 0x124);  // row_ror:4
    v += DPP_F(v, 0x128);  // row_ror:8
    return v;
}
__device__ __forceinline__ float allmax16(float v) {
    v = fmaxf(v, DPP_F(v, 0xB1));
    v = fmaxf(v, DPP_F(v, 0x4E));
    v = fmaxf(v, DPP_F(v, 0x124));
    v = fmaxf(v, DPP_F(v, 0x128));
    return v;
}

// One thread per (sample n, output capsule o). Block = 256 threads = 16 samples x 16 o.
// tid = ln*16 + o  (o in low 4 bits) so softmax-over-o lives in one 16-lane DPP row.
__global__ __launch_bounds__(256, 4) void caps_kernel(
    const float* __restrict__ x,      // [N,16,4]
    const float* __restrict__ quats,  // [16,16,4]
    const float* __restrict__ scale,  // [16,16,1]
    const float* __restrict__ trans,  // [16,16,3]
    const float* __restrict__ bias,   // [16]
    const float* __restrict__ beta,   // [16]
    const float* __restrict__ alpha,  // [16]
    float* __restrict__ out)          // [N,16,4]
{
    __shared__ __align__(16) float qs[16][16][4];  // folded scale * qn  [i][o][4]
    __shared__ __align__(16) float tr[16][16][4];  // (0, tx, ty, tz)    [i][o][4]
    __shared__ __align__(16) float xs[16][68];     // x tile, +4 float row pad

    const int tid = threadIdx.x;
    const int o   = tid & 15;
    const int ln  = tid >> 4;

    // ---- stage params: one thread per (o2,i2) entry; fold scale into qn ----
    {
        const int o2 = tid >> 4, i2 = tid & 15;
        const float4 q = ((const float4*)quats)[tid];     // quats[o2][i2][0:4]
        const float sc = scale[tid];
        const float qn2 = q.x*q.x + q.y*q.y + q.z*q.z + q.w*q.w;
        const float f = sc * rsq_fast(qn2 + EPSQ);
        qs[i2][o2][0] = q.x * f;
        qs[i2][o2][1] = q.y * f;
        qs[i2][o2][2] = q.z * f;
        qs[i2][o2][3] = q.w * f;
        tr[i2][o2][0] = 0.0f;                 // real part untranslated
        tr[i2][o2][1] = trans[tid*3 + 0];
        tr[i2][o2][2] = trans[tid*3 + 1];
        tr[i2][o2][3] = trans[tid*3 + 2];
    }
    // ---- stage x tile: 1024 contiguous floats, one float4 per thread ----
    {
        const float4 xv = ((const float4*)x)[(size_t)blockIdx.x * 256 + tid];
        *(float4*)&xs[tid >> 4][(tid & 15) * 4] = xv;
    }
    __syncthreads();

    // ---- votes[i] = (scale*qn) (x) x[n,i]  + trans   (register-resident) ----
    float4 votes[16];
    #pragma unroll
    for (int i = 0; i < 16; ++i) {
        const float4 q  = *(const float4*)&qs[i][o][0];
        const float4 t  = *(const float4*)&tr[i][o][0];
        const float4 xv = *(const float4*)&xs[ln][i * 4];
        float4 vt;
        vt.x = q.x*xv.x - q.y*xv.y - q.z*xv.z - q.w*xv.w + t.x;
        vt.y = q.x*xv.y + q.y*xv.x + q.z*xv.w - q.w*xv.z + t.y;
        vt.z = q.x*xv.z - q.y*xv.w + q.z*xv.x + q.w*xv.y + t.z;
        vt.w = q.x*xv.w + q.y*xv.z - q.z*xv.y + q.w*xv.x + t.w;
        votes[i] = vt;
    }

    float b[16];
    float4 s, v;

    // ---- routing iter 0: b==0 -> softmax is exactly uniform c = 1/16 ----
    s.x = s.y = s.z = s.w = 0.f;
    #pragma unroll
    for (int i = 0; i < 16; ++i) {
        s.x += votes[i].x; s.y += votes[i].y; s.z += votes[i].z; s.w += votes[i].w;
    }
    s.x *= 0.0625f; s.y *= 0.0625f; s.z *= 0.0625f; s.w *= 0.0625f;
    {
        const float n2 = s.x*s.x + s.y*s.y + s.z*s.z + s.w*s.w;
        const float f = n2 * rcp_fast(1.f + n2) * rsq_fast(n2 + EPSQ);
        v.x = s.x*f; v.y = s.y*f; v.z = s.z*f; v.w = s.w*f;
    }
    #pragma unroll
    for (int i = 0; i < 16; ++i)
        b[i] = v.x*votes[i].x + v.y*votes[i].y + v.z*votes[i].z + v.w*votes[i].w;

    // ---- routing iters 1..2: softmax over o via DPP all-reduce (no LDS) ----
    #pragma unroll
    for (int it = 1; it < 3; ++it) {
        float4 sn; sn.x = sn.y = sn.z = sn.w = 0.f;
        #pragma unroll
        for (int i = 0; i < 16; ++i) {
            const float bi = b[i];
            const float m  = allmax16(bi);
            const float e  = __expf(bi - m);
            const float se = allsum16(e);
            const float c  = e * rcp_fast(se);
            sn.x = fmaf(c, votes[i].x, sn.x);
            sn.y = fmaf(c, votes[i].y, sn.y);
            sn.z = fmaf(c, votes[i].z, sn.z);
            sn.w = fmaf(c, votes[i].w, sn.w);
        }
        s = sn;
        const float n2 = s.x*s.x + s.y*s.y + s.z*s.z + s.w*s.w;
        const float f = n2 * rcp_fast(1.f + n2) * rsq_fast(n2 + EPSQ);
        v.x = s.x*f; v.y = s.y*f; v.z = s.z*f; v.w = s.w*f;
        if (it == 1) {   // last iteration's b-update is dead in the reference
            #pragma unroll
            for (int i = 0; i < 16; ++i)
                b[i] += v.x*votes[i].x + v.y*votes[i].y + v.z*votes[i].z + v.w*votes[i].w;
        }
    }

    // ---- activation + store (coalesced float4 per thread) ----
    const float n2f = s.x*s.x + s.y*s.y + s.z*s.z + s.w*s.w;
    const float norm_s = sqrtf(n2f + EPSQ);
    const float tgt = beta[o] * norm_s + alpha[o] + bias[o];
    const float a = rcp_fast(1.f + __expf(-tgt));
    float4 ov;
    ov.x = v.x * a; ov.y = v.y * a; ov.z = v.z * a; ov.w = v.w * a;
    ((float4*)out)[(size_t)blockIdx.x * 256 + tid] = ov;
}

extern "C" void kernel_launch(void* const* d_in, const int* in_sizes, int n_in,
                              void* d_out, int out_size, void* d_ws, size_t ws_size,
                              hipStream_t stream) {
    const float* x     = (const float*)d_in[0];
    const float* quats = (const float*)d_in[1];
    const float* scale = (const float*)d_in[2];
    const float* trans = (const float*)d_in[3];
    const float* bias  = (const float*)d_in[4];
    const float* beta  = (const float*)d_in[5];
    const float* alpha = (const float*)d_in[6];
    float* out = (float*)d_out;

    const int N = in_sizes[0] / 64;      // x is [N,16,4]
    dim3 grid(N / 16), block(256);       // 16 samples per block
    caps_kernel<<<grid, block, 0, stream>>>(x, quats, scale, trans, bias, beta, alpha, out);
}

// Round 3
// 105.676 us; speedup vs baseline: 1.2332x; 1.0972x over previous
//
#include <hip/hip_runtime.h>
#include <math.h>

#define EPSQ 1e-8f

__device__ __forceinline__ float rcp_fast(float x) { return __builtin_amdgcn_rcpf(x); }
__device__ __forceinline__ float rsq_fast(float x) { return __builtin_amdgcn_rsqf(x); }

// DPP cross-lane move: ctrl must be a compile-time constant.
#define DPP_F(x, ctrl) \
    __int_as_float(__builtin_amdgcn_update_dpp(0, __float_as_int(x), (ctrl), 0xF, 0xF, true))

// All-reduce sum over each aligned 16-lane group (pure VALU, no LDS):
// quad butterfly (xor1, xor2) -> quad-uniform, then row_ror:4 + row_ror:8
// combine the four quads of the 16-lane DPP row.
__device__ __forceinline__ float allsum16(float v) {
    v += DPP_F(v, 0xB1);   // quad_perm [1,0,3,2]  == xor 1
    v += DPP_F(v, 0x4E);   // quad_perm [2,3,0,1]  == xor 2
    v += DPP_F(v, 0x124);  // row_ror:4
    v += DPP_F(v, 0x128);  // row_ror:8
    return v;
}

// One thread per (sample n, output capsule o). Block = 256 threads = 16 samples x 16 o.
// tid = ln*16 + o  (o in low 4 bits) so softmax-over-o lives in one 16-lane DPP row.
// launch_bounds(256,2): allow up to 256 VGPRs -- votes[16]+b[16] need ~110 live
// regs; capping at 128 (min_waves=4) made the compiler spill to scratch
// (R2: WRITE_SIZE 52 MB vs 16.4 MB of actual output).
__global__ __launch_bounds__(256, 2) void caps_kernel(
    const float* __restrict__ x,      // [N,16,4]
    const float* __restrict__ quats,  // [16,16,4]
    const float* __restrict__ scale,  // [16,16,1]
    const float* __restrict__ trans,  // [16,16,3]
    const float* __restrict__ bias,   // [16]
    const float* __restrict__ beta,   // [16]
    const float* __restrict__ alpha,  // [16]
    float* __restrict__ out)          // [N,16,4]
{
    __shared__ __align__(16) float qs[16][16][4];  // folded scale * qn  [i][o][4]
    __shared__ __align__(16) float tr[16][16][4];  // (0, tx, ty, tz)    [i][o][4]
    __shared__ __align__(16) float xs[16][68];     // x tile, +4 float row pad

    const int tid = threadIdx.x;
    const int o   = tid & 15;
    const int ln  = tid >> 4;

    // ---- stage params (transposed assignment: o2 in low bits so LDS write
    // addresses within a 16-lane group are o2*16B apart -> 2-way bank
    // aliasing (free), not the 16-way conflict of the i2-major assignment.
    // Global reads become strided but the tables are 4 KB and L2-resident.
    {
        const int o2 = tid & 15, i2 = tid >> 4;
        const int pidx = o2 * 16 + i2;                    // [o2][i2] entry
        const float4 q = ((const float4*)quats)[pidx];
        const float sc = scale[pidx];
        const float qn2 = q.x*q.x + q.y*q.y + q.z*q.z + q.w*q.w;
        const float f = sc * rsq_fast(qn2 + EPSQ);
        qs[i2][o2][0] = q.x * f;
        qs[i2][o2][1] = q.y * f;
        qs[i2][o2][2] = q.z * f;
        qs[i2][o2][3] = q.w * f;
        tr[i2][o2][0] = 0.0f;                 // real part untranslated
        tr[i2][o2][1] = trans[pidx*3 + 0];
        tr[i2][o2][2] = trans[pidx*3 + 1];
        tr[i2][o2][3] = trans[pidx*3 + 2];
    }
    // ---- stage x tile: 1024 contiguous floats, one float4 per thread ----
    {
        const float4 xv = ((const float4*)x)[(size_t)blockIdx.x * 256 + tid];
        *(float4*)&xs[tid >> 4][(tid & 15) * 4] = xv;
    }
    __syncthreads();

    // ---- votes[i] = (scale*qn) (x) x[n,i]  + trans   (register-resident) ----
    float4 votes[16];
    #pragma unroll
    for (int i = 0; i < 16; ++i) {
        const float4 q  = *(const float4*)&qs[i][o][0];
        const float4 t  = *(const float4*)&tr[i][o][0];
        const float4 xv = *(const float4*)&xs[ln][i * 4];
        float4 vt;
        vt.x = q.x*xv.x - q.y*xv.y - q.z*xv.z - q.w*xv.w + t.x;
        vt.y = q.x*xv.y + q.y*xv.x + q.z*xv.w - q.w*xv.z + t.y;
        vt.z = q.x*xv.z - q.y*xv.w + q.z*xv.x + q.w*xv.y + t.z;
        vt.w = q.x*xv.w + q.y*xv.z - q.z*xv.y + q.w*xv.x + t.w;
        votes[i] = vt;
    }

    float b[16];
    float4 s, v;

    // ---- routing iter 0: b==0 -> softmax is exactly uniform c = 1/16 ----
    s.x = s.y = s.z = s.w = 0.f;
    #pragma unroll
    for (int i = 0; i < 16; ++i) {
        s.x += votes[i].x; s.y += votes[i].y; s.z += votes[i].z; s.w += votes[i].w;
    }
    s.x *= 0.0625f; s.y *= 0.0625f; s.z *= 0.0625f; s.w *= 0.0625f;
    {
        const float n2 = s.x*s.x + s.y*s.y + s.z*s.z + s.w*s.w;
        const float f = n2 * rcp_fast(1.f + n2) * rsq_fast(n2 + EPSQ);
        v.x = s.x*f; v.y = s.y*f; v.z = s.z*f; v.w = s.w*f;
    }
    #pragma unroll
    for (int i = 0; i < 16; ++i)
        b[i] = v.x*votes[i].x + v.y*votes[i].y + v.z*votes[i].z + v.w*votes[i].w;

    // ---- routing iters 1..2: softmax over o via DPP all-reduce (no LDS).
    // Max-subtraction dropped: |b| <= ~40 here (squash-bounded v, bounded
    // votes), so exp never overflows fp32 and softmax is scale-invariant.
    #pragma unroll
    for (int it = 1; it < 3; ++it) {
        float4 sn; sn.x = sn.y = sn.z = sn.w = 0.f;
        #pragma unroll
        for (int i = 0; i < 16; ++i) {
            const float e  = __expf(b[i]);
            const float se = allsum16(e);
            const float c  = e * rcp_fast(se);
            sn.x = fmaf(c, votes[i].x, sn.x);
            sn.y = fmaf(c, votes[i].y, sn.y);
            sn.z = fmaf(c, votes[i].z, sn.z);
            sn.w = fmaf(c, votes[i].w, sn.w);
        }
        s = sn;
        const float n2 = s.x*s.x + s.y*s.y + s.z*s.z + s.w*s.w;
        const float f = n2 * rcp_fast(1.f + n2) * rsq_fast(n2 + EPSQ);
        v.x = s.x*f; v.y = s.y*f; v.z = s.z*f; v.w = s.w*f;
        if (it == 1) {   // last iteration's b-update is dead in the reference
            #pragma unroll
            for (int i = 0; i < 16; ++i)
                b[i] += v.x*votes[i].x + v.y*votes[i].y + v.z*votes[i].z + v.w*votes[i].w;
        }
    }

    // ---- activation + store (coalesced float4 per thread) ----
    const float n2f = s.x*s.x + s.y*s.y + s.z*s.z + s.w*s.w;
    const float norm_s = sqrtf(n2f + EPSQ);
    const float tgt = beta[o] * norm_s + alpha[o] + bias[o];
    const float a = rcp_fast(1.f + __expf(-tgt));
    float4 ov;
    ov.x = v.x * a; ov.y = v.y * a; ov.z = v.z * a; ov.w = v.w * a;
    ((float4*)out)[(size_t)blockIdx.x * 256 + tid] = ov;
}

extern "C" void kernel_launch(void* const* d_in, const int* in_sizes, int n_in,
                              void* d_out, int out_size, void* d_ws, size_t ws_size,
                              hipStream_t stream) {
    const float* x     = (const float*)d_in[0];
    const float* quats = (const float*)d_in[1];
    const float* scale = (const float*)d_in[2];
    const float* trans = (const float*)d_in[3];
    const float* bias  = (const float*)d_in[4];
    const float* beta  = (const float*)d_in[5];
    const float* alpha = (const float*)d_in[6];
    float* out = (float*)d_out;

    const int N = in_sizes[0] / 64;      // x is [N,16,4]
    dim3 grid(N / 16), block(256);       // 16 samples per block
    caps_kernel<<<grid, block, 0, stream>>>(x, quats, scale, trans, bias, beta, alpha, out);
}

// Round 4
// 97.873 us; speedup vs baseline: 1.3315x; 1.0797x over previous
//
#include <hip/hip_runtime.h>
#include <math.h>

#define EPSQ 1e-8f
#define LOG2E 1.4426950408889634f

typedef float f2 __attribute__((ext_vector_type(2)));

__device__ __forceinline__ float rcp_fast(float x) { return __builtin_amdgcn_rcpf(x); }
__device__ __forceinline__ float rsq_fast(float x) { return __builtin_amdgcn_rsqf(x); }
__device__ __forceinline__ f2 pk_fma(f2 a, f2 b, f2 c) { return __builtin_elementwise_fma(a, b, c); }

// DPP cross-lane move: ctrl must be a compile-time constant.
#define DPP_F(x, ctrl) \
    __int_as_float(__builtin_amdgcn_update_dpp(0, __float_as_int(x), (ctrl), 0xF, 0xF, true))

// All-reduce sum over each aligned 16-lane group (pure VALU, no LDS).
__device__ __forceinline__ float allsum16(float v) {
    v += DPP_F(v, 0xB1);   // quad_perm [1,0,3,2]  == xor 1
    v += DPP_F(v, 0x4E);   // quad_perm [2,3,0,1]  == xor 2
    v += DPP_F(v, 0x124);  // row_ror:4
    v += DPP_F(v, 0x128);  // row_ror:8
    return v;
}

// One thread per (sample n, output capsule o). Block = 256 = 16 samples x 16 o.
// tid = ln*16 + o (o in low 4 bits): softmax-over-o lives in one 16-lane DPP row.
// launch_bounds(256,2): ~120+ live VGPRs; capping at 128 caused scratch spill (R2).
__global__ __launch_bounds__(256, 2) void caps_kernel(
    const float* __restrict__ x,      // [N,16,4]
    const float* __restrict__ quats,  // [16,16,4]
    const float* __restrict__ scale,  // [16,16,1]
    const float* __restrict__ trans,  // [16,16,3]
    const float* __restrict__ bias,   // [16]
    const float* __restrict__ beta,   // [16]
    const float* __restrict__ alpha,  // [16]
    float* __restrict__ out)          // [N,16,4]
{
    __shared__ __align__(16) float qs[16][16][4];  // folded scale * qn  [i][o][4]
    __shared__ __align__(16) float tr[16][16][4];  // (0, tx, ty, tz)    [i][o][4]
    __shared__ __align__(16) float xs[16][68];     // x tile, +4 float row pad

    const int tid = threadIdx.x;
    const int o   = tid & 15;
    const int ln  = tid >> 4;

    // ---- stage params (o2 in low bits: LDS write addrs 16B apart within a
    // 16-lane group -> 2-way bank aliasing (free), vs 16-way for i2-major).
    {
        const int o2 = tid & 15, i2 = tid >> 4;
        const int pidx = o2 * 16 + i2;                    // [o2][i2] entry
        const float4 q = ((const float4*)quats)[pidx];
        const float sc = scale[pidx];
        const float qn2 = q.x*q.x + q.y*q.y + q.z*q.z + q.w*q.w;
        const float f = sc * rsq_fast(qn2 + EPSQ);
        qs[i2][o2][0] = q.x * f;
        qs[i2][o2][1] = q.y * f;
        qs[i2][o2][2] = q.z * f;
        qs[i2][o2][3] = q.w * f;
        tr[i2][o2][0] = 0.0f;                 // real part untranslated
        tr[i2][o2][1] = trans[pidx*3 + 0];
        tr[i2][o2][2] = trans[pidx*3 + 1];
        tr[i2][o2][3] = trans[pidx*3 + 2];
    }
    // ---- stage x tile: 1024 contiguous floats, one float4 per thread ----
    {
        const float4 xv = ((const float4*)x)[(size_t)blockIdx.x * 256 + tid];
        *(float4*)&xs[tid >> 4][(tid & 15) * 4] = xv;
    }
    __syncthreads();

    // ---- votes[i] = (scale*qn) (x) x[n,i] + trans, packed fp32 pairs ------
    // q4=(qw,qx,qy,qz), x4=(xw,xx,xy,xz); vote halves (w,x) and (y,z).
    f2 vwx[16], vyz[16];
    #pragma unroll
    for (int i = 0; i < 16; ++i) {
        const float4 q4 = *(const float4*)&qs[i][o][0];
        const float4 t4 = *(const float4*)&tr[i][o][0];
        const float4 x4 = *(const float4*)&xs[ln][i * 4];
        f2 a, b2;
        // (qw*xw - qx*xx - qy*xy - qz*xz , qw*xx + qx*xw + qy*xz - qz*xy)
        a  = f2{q4.x, q4.x} * f2{x4.x, x4.y};
        a  = pk_fma(f2{-q4.y,  q4.y}, f2{x4.y, x4.x}, a);
        a  = pk_fma(f2{-q4.z,  q4.z}, f2{x4.z, x4.w}, a);
        a  = pk_fma(f2{-q4.w, -q4.w}, f2{x4.w, x4.z}, a);
        a += f2{t4.x, t4.y};
        // (qw*xy - qx*xz + qy*xw + qz*xx , qw*xz + qx*xy - qy*xx + qz*xw)
        b2  = f2{q4.x, q4.x} * f2{x4.z, x4.w};
        b2  = pk_fma(f2{-q4.y,  q4.y}, f2{x4.w, x4.z}, b2);
        b2  = pk_fma(f2{ q4.z, -q4.z}, f2{x4.x, x4.y}, b2);
        b2  = pk_fma(f2{ q4.w,  q4.w}, f2{x4.y, x4.x}, b2);
        b2 += f2{t4.z, t4.w};
        vwx[i] = a; vyz[i] = b2;
    }

    float b[16];                 // routing logits, kept in log2 domain
    f2 s01, s23, v01, v23;

    // ---- routing iter 0: b==0 -> softmax exactly uniform c = 1/16 ----
    s01 = f2{0.f, 0.f}; s23 = f2{0.f, 0.f};
    #pragma unroll
    for (int i = 0; i < 16; ++i) { s01 += vwx[i]; s23 += vyz[i]; }
    s01 *= 0.0625f; s23 *= 0.0625f;
    {
        const float n2 = s01.x*s01.x + s01.y*s01.y + s23.x*s23.x + s23.y*s23.y;
        const float f = n2 * rcp_fast(1.f + n2) * rsq_fast(n2 + EPSQ);
        v01 = s01 * f; v23 = s23 * f;
    }
    {   // b_log2[i] = log2e * dot(v, votes[i])
        const f2 vl01 = v01 * LOG2E, vl23 = v23 * LOG2E;
        #pragma unroll
        for (int i = 0; i < 16; ++i) {
            f2 d = vl01 * vwx[i];
            d = pk_fma(vl23, vyz[i], d);
            b[i] = d.x + d.y;
        }
    }

    // ---- routing iters 1..2: softmax over o via DPP all-reduce.
    // Max-subtraction dropped: |b_log2| <= ~60 -> exp2 never overflows fp32.
    #pragma unroll
    for (int it = 1; it < 3; ++it) {
        f2 sn01 = f2{0.f, 0.f}, sn23 = f2{0.f, 0.f};
        #pragma unroll
        for (int i = 0; i < 16; ++i) {
            const float e  = __builtin_amdgcn_exp2f(b[i]);
            const float se = allsum16(e);
            const float c  = e * rcp_fast(se);
            sn01 = pk_fma(f2{c, c}, vwx[i], sn01);
            sn23 = pk_fma(f2{c, c}, vyz[i], sn23);
        }
        s01 = sn01; s23 = sn23;
        const float n2 = s01.x*s01.x + s01.y*s01.y + s23.x*s23.x + s23.y*s23.y;
        const float f = n2 * rcp_fast(1.f + n2) * rsq_fast(n2 + EPSQ);
        v01 = s01 * f; v23 = s23 * f;
        if (it == 1) {   // last iteration's b-update is dead in the reference
            const f2 vl01 = v01 * LOG2E, vl23 = v23 * LOG2E;
            #pragma unroll
            for (int i = 0; i < 16; ++i) {
                f2 d = vl01 * vwx[i];
                d = pk_fma(vl23, vyz[i], d);
                b[i] += d.x + d.y;
            }
        }
    }

    // ---- activation + store (coalesced float4 per thread) ----
    const float n2f = s01.x*s01.x + s01.y*s01.y + s23.x*s23.x + s23.y*s23.y;
    const float norm_s = sqrtf(n2f + EPSQ);
    const float tgt = beta[o] * norm_s + alpha[o] + bias[o];
    const float a = rcp_fast(1.f + __builtin_amdgcn_exp2f(-tgt * LOG2E));
    float4 ov;
    ov.x = v01.x * a; ov.y = v01.y * a; ov.z = v23.x * a; ov.w = v23.y * a;
    ((float4*)out)[(size_t)blockIdx.x * 256 + tid] = ov;
}

extern "C" void kernel_launch(void* const* d_in, const int* in_sizes, int n_in,
                              void* d_out, int out_size, void* d_ws, size_t ws_size,
                              hipStream_t stream) {
    const float* x     = (const float*)d_in[0];
    const float* quats = (const float*)d_in[1];
    const float* scale = (const float*)d_in[2];
    const float* trans = (const float*)d_in[3];
    const float* bias  = (const float*)d_in[4];
    const float* beta  = (const float*)d_in[5];
    const float* alpha = (const float*)d_in[6];
    float* out = (float*)d_out;

    const int N = in_sizes[0] / 64;      // x is [N,16,4]
    dim3 grid(N / 16), block(256);       // 16 samples per block
    caps_kernel<<<grid, block, 0, stream>>>(x, quats, scale, trans, bias, beta, alpha, out);
}

// Round 5
// 97.586 us; speedup vs baseline: 1.3354x; 1.0029x over previous
//
#include <hip/hip_runtime.h>
#include <math.h>

#define EPSQ 1e-8f
#define LOG2E 1.4426950408889634f

typedef float f2 __attribute__((ext_vector_type(2)));

__device__ __forceinline__ float rcp_fast(float x) { return __builtin_amdgcn_rcpf(x); }
__device__ __forceinline__ float rsq_fast(float x) { return __builtin_amdgcn_rsqf(x); }
__device__ __forceinline__ f2 pk_fma(f2 a, f2 b, f2 c) { return __builtin_elementwise_fma(a, b, c); }

// DPP cross-lane move: ctrl must be a compile-time constant.
#define DPP_F(x, ctrl) \
    __int_as_float(__builtin_amdgcn_update_dpp(0, __float_as_int(x), (ctrl), 0xF, 0xF, true))

// All-reduce sum over each aligned 16-lane group (pure VALU, no LDS).
__device__ __forceinline__ float allsum16(float v) {
    v += DPP_F(v, 0xB1);   // quad_perm [1,0,3,2]  == xor 1
    v += DPP_F(v, 0x4E);   // quad_perm [2,3,0,1]  == xor 2
    v += DPP_F(v, 0x124);  // row_ror:4
    v += DPP_F(v, 0x128);  // row_ror:8
    return v;
}

// One thread per (sample n, output capsule o). Block = 256 = 16 samples x 16 o.
// tid = ln*16 + o (o in low 4 bits): softmax-over-o lives in one 16-lane DPP row.
// launch_bounds(256,3): cap ~168 VGPR -> >=3 waves/SIMD for latency hiding.
// (256,2) let the allocator run to 2 waves/SIMD; (256,4)=128 cap spilled (R2).
__global__ __launch_bounds__(256, 3) void caps_kernel(
    const float* __restrict__ x,      // [N,16,4]
    const float* __restrict__ quats,  // [16,16,4]
    const float* __restrict__ scale,  // [16,16,1]
    const float* __restrict__ trans,  // [16,16,3]
    const float* __restrict__ bias,   // [16]
    const float* __restrict__ beta,   // [16]
    const float* __restrict__ alpha,  // [16]
    float* __restrict__ out)          // [N,16,4]
{
    __shared__ __align__(16) float qs[16][16][4];  // folded scale * qn  [i][o][4]
    __shared__ __align__(16) float tr[16][16][4];  // (0, tx, ty, tz)    [i][o][4]
    __shared__ __align__(16) float xs[16][68];     // x tile, +4 float row pad

    const int tid = threadIdx.x;
    const int o   = tid & 15;
    const int ln  = tid >> 4;

    // ---- stage params (o2 in low bits: LDS write addrs 16B apart within a
    // 16-lane group -> 2-way bank aliasing (free), vs 16-way for i2-major).
    {
        const int o2 = tid & 15, i2 = tid >> 4;
        const int pidx = o2 * 16 + i2;                    // [o2][i2] entry
        const float4 q = ((const float4*)quats)[pidx];
        const float sc = scale[pidx];
        const float qn2 = q.x*q.x + q.y*q.y + q.z*q.z + q.w*q.w;
        const float f = sc * rsq_fast(qn2 + EPSQ);
        qs[i2][o2][0] = q.x * f;
        qs[i2][o2][1] = q.y * f;
        qs[i2][o2][2] = q.z * f;
        qs[i2][o2][3] = q.w * f;
        tr[i2][o2][0] = 0.0f;                 // real part untranslated
        tr[i2][o2][1] = trans[pidx*3 + 0];
        tr[i2][o2][2] = trans[pidx*3 + 1];
        tr[i2][o2][3] = trans[pidx*3 + 2];
    }
    // ---- stage x tile: 1024 contiguous floats, one float4 per thread ----
    {
        const float4 xv = ((const float4*)x)[(size_t)blockIdx.x * 256 + tid];
        *(float4*)&xs[tid >> 4][(tid & 15) * 4] = xv;
    }
    __syncthreads();

    // ---- votes[i] = (scale*qn) (x) x[n,i] + trans, packed fp32 pairs ------
    // q4=(qw,qx,qy,qz), x4=(xw,xx,xy,xz); vote halves (w,x) and (y,z).
    // trans folded in as the fma accumulator init: 8 pk_fma per vote, no adds.
    f2 vwx[16], vyz[16];
    #pragma unroll
    for (int i = 0; i < 16; ++i) {
        const float4 q4 = *(const float4*)&qs[i][o][0];
        const float4 t4 = *(const float4*)&tr[i][o][0];
        const float4 x4 = *(const float4*)&xs[ln][i * 4];
        f2 a, b2;
        // (qw*xw - qx*xx - qy*xy - qz*xz , qw*xx + qx*xw + qy*xz - qz*xy) + (0,tx)
        a = pk_fma(f2{ q4.x,  q4.x}, f2{x4.x, x4.y}, f2{t4.x, t4.y});
        a = pk_fma(f2{-q4.y,  q4.y}, f2{x4.y, x4.x}, a);
        a = pk_fma(f2{-q4.z,  q4.z}, f2{x4.z, x4.w}, a);
        a = pk_fma(f2{-q4.w, -q4.w}, f2{x4.w, x4.z}, a);
        // (qw*xy - qx*xz + qy*xw + qz*xx , qw*xz + qx*xy - qy*xx + qz*xw) + (ty,tz)
        b2 = pk_fma(f2{ q4.x,  q4.x}, f2{x4.z, x4.w}, f2{t4.z, t4.w});
        b2 = pk_fma(f2{-q4.y,  q4.y}, f2{x4.w, x4.z}, b2);
        b2 = pk_fma(f2{ q4.z, -q4.z}, f2{x4.x, x4.y}, b2);
        b2 = pk_fma(f2{ q4.w,  q4.w}, f2{x4.y, x4.x}, b2);
        vwx[i] = a; vyz[i] = b2;
    }

    float b[16];                 // routing logits, kept in log2 domain
    f2 s01, s23, v01, v23;

    // ---- routing iter 0: b==0 -> softmax exactly uniform c = 1/16.
    // Scaling folded into the squash factor: s = u/16, n2 = |u|^2/256.
    {
        f2 u01 = f2{0.f, 0.f}, u23 = f2{0.f, 0.f};
        #pragma unroll
        for (int i = 0; i < 16; ++i) { u01 += vwx[i]; u23 += vyz[i]; }
        f2 d = u01 * u01;
        d = pk_fma(u23, u23, d);
        const float n2 = (d.x + d.y) * (1.0f / 256.0f);
        const float f = n2 * rcp_fast(1.f + n2) * rsq_fast(n2 + EPSQ) * 0.0625f;
        v01 = u01 * f; v23 = u23 * f;
        s01 = u01 * 0.0625f; s23 = u23 * 0.0625f;
    }
    {   // b_log2[i] = log2e * dot(v, votes[i])
        const f2 vl01 = v01 * LOG2E, vl23 = v23 * LOG2E;
        #pragma unroll
        for (int i = 0; i < 16; ++i) {
            f2 d = vl01 * vwx[i];
            d = pk_fma(vl23, vyz[i], d);
            b[i] = d.x + d.y;
        }
    }

    // ---- routing iters 1..2: softmax over o via DPP all-reduce.
    // Max-subtraction dropped: |b_log2| <= ~60 -> exp2 never overflows fp32.
    #pragma unroll
    for (int it = 1; it < 3; ++it) {
        f2 sn01 = f2{0.f, 0.f}, sn23 = f2{0.f, 0.f};
        #pragma unroll
        for (int i = 0; i < 16; ++i) {
            const float e  = __builtin_amdgcn_exp2f(b[i]);
            const float se = allsum16(e);
            const float c  = e * rcp_fast(se);
            sn01 = pk_fma(f2{c, c}, vwx[i], sn01);
            sn23 = pk_fma(f2{c, c}, vyz[i], sn23);
        }
        s01 = sn01; s23 = sn23;
        const float n2 = s01.x*s01.x + s01.y*s01.y + s23.x*s23.x + s23.y*s23.y;
        const float f = n2 * rcp_fast(1.f + n2) * rsq_fast(n2 + EPSQ);
        v01 = s01 * f; v23 = s23 * f;
        if (it == 1) {   // last iteration's b-update is dead in the reference
            const f2 vl01 = v01 * LOG2E, vl23 = v23 * LOG2E;
            #pragma unroll
            for (int i = 0; i < 16; ++i) {
                f2 d = vl01 * vwx[i];
                d = pk_fma(vl23, vyz[i], d);
                b[i] += d.x + d.y;
            }
        }
    }

    // ---- activation + store (coalesced float4 per thread) ----
    const float n2f = s01.x*s01.x + s01.y*s01.y + s23.x*s23.x + s23.y*s23.y;
    const float norm_s = sqrtf(n2f + EPSQ);
    const float tgt = beta[o] * norm_s + alpha[o] + bias[o];
    const float a = rcp_fast(1.f + __builtin_amdgcn_exp2f(-tgt * LOG2E));
    float4 ov;
    ov.x = v01.x * a; ov.y = v01.y * a; ov.z = v23.x * a; ov.w = v23.y * a;
    ((float4*)out)[(size_t)blockIdx.x * 256 + tid] = ov;
}

extern "C" void kernel_launch(void* const* d_in, const int* in_sizes, int n_in,
                              void* d_out, int out_size, void* d_ws, size_t ws_size,
                              hipStream_t stream) {
    const float* x     = (const float*)d_in[0];
    const float* quats = (const float*)d_in[1];
    const float* scale = (const float*)d_in[2];
    const float* trans = (const float*)d_in[3];
    const float* bias  = (const float*)d_in[4];
    const float* beta  = (const float*)d_in[5];
    const float* alpha = (const float*)d_in[6];
    float* out = (float*)d_out;

    const int N = in_sizes[0] / 64;      // x is [N,16,4]
    dim3 grid(N / 16), block(256);       // 16 samples per block
    caps_kernel<<<grid, block, 0, stream>>>(x, quats, scale, trans, bias, beta, alpha, out);
}

// Round 6
// 97.559 us; speedup vs baseline: 1.3358x; 1.0003x over previous
//
#include <hip/hip_runtime.h>
#include <math.h>

#define EPSQ 1e-8f
#define LOG2E 1.4426950408889634f

typedef float f2 __attribute__((ext_vector_type(2)));

__device__ __forceinline__ float rcp_fast(float x) { return __builtin_amdgcn_rcpf(x); }
__device__ __forceinline__ float rsq_fast(float x) { return __builtin_amdgcn_rsqf(x); }
__device__ __forceinline__ f2 pk_fma(f2 a, f2 b, f2 c) { return __builtin_elementwise_fma(a, b, c); }

// DPP cross-lane move: ctrl must be a compile-time constant.
#define DPP_F(x, ctrl) \
    __int_as_float(__builtin_amdgcn_update_dpp(0, __float_as_int(x), (ctrl), 0xF, 0xF, true))

// All-reduce sum over each aligned 16-lane group (pure VALU, no LDS).
__device__ __forceinline__ float allsum16(float v) {
    v += DPP_F(v, 0xB1);   // quad_perm [1,0,3,2]  == xor 1
    v += DPP_F(v, 0x4E);   // quad_perm [2,3,0,1]  == xor 2
    v += DPP_F(v, 0x124);  // row_ror:4
    v += DPP_F(v, 0x128);  // row_ror:8
    return v;
}

// One thread per (sample n, output capsule o). Block = 256 = 16 samples x 16 o.
// tid = ln*16 + o (o in low 4 bits): softmax-over-o lives in one 16-lane DPP row.
// launch_bounds(256,4): 128-VGPR cap -> 4 waves/SIMD. The persistent b[16]
// array was eliminated (recomputed from the running v-sum in log2 domain,
// same inst count) so live state is ~95 regs -- should fit without the
// scratch spill R2 hit at this cap. Watch WRITE_SIZE for the spill signature.
__global__ __launch_bounds__(256, 4) void caps_kernel(
    const float* __restrict__ x,      // [N,16,4]
    const float* __restrict__ quats,  // [16,16,4]
    const float* __restrict__ scale,  // [16,16,1]
    const float* __restrict__ trans,  // [16,16,3]
    const float* __restrict__ bias,   // [16]
    const float* __restrict__ beta,   // [16]
    const float* __restrict__ alpha,  // [16]
    float* __restrict__ out)          // [N,16,4]
{
    __shared__ __align__(16) float qs[16][16][4];  // folded scale * qn  [i][o][4]
    __shared__ __align__(16) float tr[16][16][4];  // (0, tx, ty, tz)    [i][o][4]
    __shared__ __align__(16) float xs[16][68];     // x tile, +4 float row pad

    const int tid = threadIdx.x;
    const int o   = tid & 15;
    const int ln  = tid >> 4;

    // ---- stage params (o2 in low bits: LDS write addrs 16B apart within a
    // 16-lane group -> 2-way bank aliasing (free), vs 16-way for i2-major).
    {
        const int o2 = tid & 15, i2 = tid >> 4;
        const int pidx = o2 * 16 + i2;                    // [o2][i2] entry
        const float4 q = ((const float4*)quats)[pidx];
        const float sc = scale[pidx];
        const float qn2 = q.x*q.x + q.y*q.y + q.z*q.z + q.w*q.w;
        const float f = sc * rsq_fast(qn2 + EPSQ);
        qs[i2][o2][0] = q.x * f;
        qs[i2][o2][1] = q.y * f;
        qs[i2][o2][2] = q.z * f;
        qs[i2][o2][3] = q.w * f;
        tr[i2][o2][0] = 0.0f;                 // real part untranslated
        tr[i2][o2][1] = trans[pidx*3 + 0];
        tr[i2][o2][2] = trans[pidx*3 + 1];
        tr[i2][o2][3] = trans[pidx*3 + 2];
    }
    // ---- stage x tile: 1024 contiguous floats, one float4 per thread ----
    {
        const float4 xv = ((const float4*)x)[(size_t)blockIdx.x * 256 + tid];
        *(float4*)&xs[tid >> 4][(tid & 15) * 4] = xv;
    }
    __syncthreads();

    // ---- votes[i] = (scale*qn) (x) x[n,i] + trans, packed fp32 pairs ------
    // q4=(qw,qx,qy,qz), x4=(xw,xx,xy,xz); vote halves (w,x) and (y,z).
    // trans folded in as the fma accumulator init: 8 pk_fma per vote, no adds.
    f2 vwx[16], vyz[16];
    #pragma unroll
    for (int i = 0; i < 16; ++i) {
        const float4 q4 = *(const float4*)&qs[i][o][0];
        const float4 t4 = *(const float4*)&tr[i][o][0];
        const float4 x4 = *(const float4*)&xs[ln][i * 4];
        f2 a, b2;
        // (qw*xw - qx*xx - qy*xy - qz*xz , qw*xx + qx*xw + qy*xz - qz*xy) + (0,tx)
        a = pk_fma(f2{ q4.x,  q4.x}, f2{x4.x, x4.y}, f2{t4.x, t4.y});
        a = pk_fma(f2{-q4.y,  q4.y}, f2{x4.y, x4.x}, a);
        a = pk_fma(f2{-q4.z,  q4.z}, f2{x4.z, x4.w}, a);
        a = pk_fma(f2{-q4.w, -q4.w}, f2{x4.w, x4.z}, a);
        // (qw*xy - qx*xz + qy*xw + qz*xx , qw*xz + qx*xy - qy*xx + qz*xw) + (ty,tz)
        b2 = pk_fma(f2{ q4.x,  q4.x}, f2{x4.z, x4.w}, f2{t4.z, t4.w});
        b2 = pk_fma(f2{-q4.y,  q4.y}, f2{x4.w, x4.z}, b2);
        b2 = pk_fma(f2{ q4.z, -q4.z}, f2{x4.x, x4.y}, b2);
        b2 = pk_fma(f2{ q4.w,  q4.w}, f2{x4.y, x4.x}, b2);
        vwx[i] = a; vyz[i] = b2;
    }

    // Running log2-domain logit generator: b_i = dot(vl, votes_i), where
    // vl = log2e * (v0)            for iter 1,
    // vl = log2e * (v0 + v1)       for iter 2.
    f2 vl01, vl23;       // current generator
    f2 v001, v023;       // v0 (kept to form v0+v1)
    f2 s01, s23, v01, v23;

    // ---- routing iter 0: b==0 -> softmax exactly uniform c = 1/16.
    // Scaling folded into the squash factor: s = u/16, n2 = |u|^2/256.
    {
        f2 u01 = f2{0.f, 0.f}, u23 = f2{0.f, 0.f};
        #pragma unroll
        for (int i = 0; i < 16; ++i) { u01 += vwx[i]; u23 += vyz[i]; }
        f2 d = u01 * u01;
        d = pk_fma(u23, u23, d);
        const float n2 = (d.x + d.y) * (1.0f / 256.0f);
        const float f = n2 * rcp_fast(1.f + n2) * rsq_fast(n2 + EPSQ) * 0.0625f;
        v001 = u01 * f; v023 = u23 * f;
        vl01 = v001 * LOG2E; vl23 = v023 * LOG2E;
    }

    // ---- routing iters 1..2: softmax over o via DPP all-reduce.
    // Max-subtraction dropped: |b_log2| <= ~60 -> exp2 never overflows fp32.
    #pragma unroll
    for (int it = 1; it < 3; ++it) {
        f2 sn01 = f2{0.f, 0.f}, sn23 = f2{0.f, 0.f};
        #pragma unroll
        for (int i = 0; i < 16; ++i) {
            f2 d = vl01 * vwx[i];
            d = pk_fma(vl23, vyz[i], d);
            const float e  = __builtin_amdgcn_exp2f(d.x + d.y);
            const float se = allsum16(e);
            const float c  = e * rcp_fast(se);
            sn01 = pk_fma(f2{c, c}, vwx[i], sn01);
            sn23 = pk_fma(f2{c, c}, vyz[i], sn23);
        }
        s01 = sn01; s23 = sn23;
        const float n2 = s01.x*s01.x + s01.y*s01.y + s23.x*s23.x + s23.y*s23.y;
        const float f = n2 * rcp_fast(1.f + n2) * rsq_fast(n2 + EPSQ);
        v01 = s01 * f; v23 = s23 * f;
        if (it == 1) {   // generator for iter 2: log2e * (v0 + v1)
            vl01 = (v001 + v01) * LOG2E;
            vl23 = (v023 + v23) * LOG2E;
        }
    }

    // ---- activation + store (coalesced float4 per thread) ----
    const float n2f = s01.x*s01.x + s01.y*s01.y + s23.x*s23.x + s23.y*s23.y;
    const float norm_s = sqrtf(n2f + EPSQ);
    const float tgt = beta[o] * norm_s + alpha[o] + bias[o];
    const float a = rcp_fast(1.f + __builtin_amdgcn_exp2f(-tgt * LOG2E));
    float4 ov;
    ov.x = v01.x * a; ov.y = v01.y * a; ov.z = v23.x * a; ov.w = v23.y * a;
    ((float4*)out)[(size_t)blockIdx.x * 256 + tid] = ov;
}

extern "C" void kernel_launch(void* const* d_in, const int* in_sizes, int n_in,
                              void* d_out, int out_size, void* d_ws, size_t ws_size,
                              hipStream_t stream) {
    const float* x     = (const float*)d_in[0];
    const float* quats = (const float*)d_in[1];
    const float* scale = (const float*)d_in[2];
    const float* trans = (const float*)d_in[3];
    const float* bias  = (const float*)d_in[4];
    const float* beta  = (const float*)d_in[5];
    const float* alpha = (const float*)d_in[6];
    float* out = (float*)d_out;

    const int N = in_sizes[0] / 64;      // x is [N,16,4]
    dim3 grid(N / 16), block(256);       // 16 samples per block
    caps_kernel<<<grid, block, 0, stream>>>(x, quats, scale, trans, bias, beta, alpha, out);
}